// Round 8
// baseline (250.199 us; speedup 1.0000x reference)
//
#include <hip/hip_runtime.h>
#include <hip/hip_bf16.h>
#include <utility>

typedef __bf16        bf16x8 __attribute__((ext_vector_type(8)));
typedef float         f32x16 __attribute__((ext_vector_type(16)));
typedef unsigned int  u32x4  __attribute__((ext_vector_type(4)));
typedef unsigned int   u32;
typedef unsigned short u16;

template<int N> using IC = std::integral_constant<int, N>;

__device__ __forceinline__ u16 f32_to_bf16(float f) {
    u32 u = __builtin_bit_cast(u32, f);
    u = (u + 0x7FFFu + ((u >> 16) & 1u)) >> 16;
    return (u16)u;
}
__device__ __forceinline__ u32 pack2bf(float a, float b) {
    return (u32)f32_to_bf16(a) | ((u32)f32_to_bf16(b) << 16);
}

// ---------------- kernel 1: build conv weights, bf16, layout [tap][oc][ic]
__global__ void build_c(const float* __restrict__ wxx,
                        const float* __restrict__ wid,
                        const float* __restrict__ XX,
                        const float* __restrict__ ident,
                        const int*   __restrict__ indsxx,
                        const int*   __restrict__ indsid,
                        u16*         __restrict__ cb)
{
    int idx = blockIdx.x * 256 + threadIdx.x;          // 25*128*128 = 409600
    if (idx >= 25 * 128 * 128) return;
    int b = idx & 127;            // ic2
    int a = (idx >> 7) & 127;     // oc2
    int t = idx >> 14;            // kh*5+kw
    int w2 = (a >> 1) * 64 + (b >> 1);
    float v = wxx[w2 * 5 + indsxx[t]] * XX[(a * 128 + b) * 25 + t]
            + ident[a * 128 + b]      * wid[w2 * 6 + indsid[t]];
    cb[idx] = f32_to_bf16(v);
}

// ---------------- kernel 2: implicit-GEMM conv, 32x32x16 bf16 MFMA
// 256 thr = 4 waves (2 oc x 2 w). Block: 64 oc x 4 rows x 64 w. Wave: 32oc x 4r x 32w
// (acc = 64 AGPR -> A double-buffer affordable). 8 stages of 16 ic; 5 clusters/stage;
// fine interleave per cluster: A(next) issue | x-unit issue | 8 ds_read + 20 MFMA | write.
// Raw s_barrier + lgkmcnt(0) only at stage end (A-prefetch stays in flight).
constexpr int LDSROW = 68 * 48;        // 3264 B
constexpr int LDSBUF = 8 * LDSROW;     // 26112 B

__global__ void __launch_bounds__(256, 2)
conv_mfma(const float* __restrict__ x,
          const u16*   __restrict__ cb,
          float*       __restrict__ out)
{
    __shared__ unsigned char lds[2 * LDSBUF];

    const int tid    = threadIdx.x;
    const int lane   = tid & 63;
    const int wv     = tid >> 6;
    const int wave_m = wv & 1;                           // oc half of 64
    const int wave_q = wv >> 1;                          // w half of 64
    const int l31    = lane & 31;
    const int h2     = lane >> 5;                        // k-half within K=16

    // bijective XCD swizzle: 2048 blocks, 256 consecutive tiles per XCD
    const int bid = blockIdx.x;
    const int swz = (bid & 7) * 256 + (bid >> 3);
    const int bo  = swz & 1;                             // oc group (innermost: L2 x-reuse)
    const int wq  = (swz >> 1) & 1;
    const int ht  = (swz >> 2) & 31;
    const int bb  = swz >> 7;                            // batch
    const int h0  = ht << 2;
    const int w0  = wq << 6;
    const int ocb = bo << 6;

    // staging map: thread -> (w col 0..63, 8-ic half, row parity)
    const int wc  = tid & 63;
    const int ic8 = (tid >> 6) & 1;
    const int rh  = (tid >> 7) & 1;

    // halo map (threads 0..63): 4 cols x 2 ic8 x 8 rows
    const int hsel  = tid & 3;
    const int wcolH = (hsel < 2) ? (hsel - 2) : (62 + hsel);   // -2,-1,64,65
    const int ic8H  = (tid >> 2) & 1;
    const int rH    = tid >> 3;                          // 0..7 (tid<64)
    const int hIdxH = wcolH + 2;                         // 0,1,66,67

    f32x16 acc[4];                                       // 4 output rows, 64 AGPR
    #pragma unroll
    for (int j = 0; j < 4; ++j)
        #pragma unroll
        for (int k = 0; k < 16; ++k) acc[j][k] = 0.f;

    float  pf[4][8];                                     // x in-flight units
    float  pfh[8];                                       // halo unit
    bf16x8 A[2][5];                                      // A dbuf [parity][kh]

    const float* xbase = x + (size_t)bb * (128 * 16384);
    const u16*   cbA0  = cb + (ocb + wave_m * 32 + l31) * 128 + h2 * 8;

    auto ALOAD = [&](auto Pc, auto KWc, int s) {         // cluster (KW) of stage s
        constexpr int P  = decltype(Pc)::value;
        constexpr int KW = decltype(KWc)::value;
        const u16* ab = cbA0 + KW * 16384 + s * 16;
        #pragma unroll
        for (int kh = 0; kh < 5; ++kh)
            A[P][kh] = *reinterpret_cast<const bf16x8*>(ab + kh * 81920);
    };

    auto ISSUE = [&](auto Uc, int s) {
        constexpr int U = decltype(Uc)::value;
        const int hp = h0 - 2 + 2 * U + rh;
        if ((unsigned)hp < 128u) {
            const float* px = xbase + (size_t)(s * 16 + ic8 * 8) * 16384 + hp * 128 + w0 + wc;
            #pragma unroll
            for (int j = 0; j < 8; ++j) pf[U][j] = px[(size_t)j * 16384];
        } else {
            #pragma unroll
            for (int j = 0; j < 8; ++j) pf[U][j] = 0.f;
        }
    };

    auto ISSUEH = [&](int s) {
        if (tid < 64) {
            const int hp = h0 - 2 + rH;
            const int gc = w0 + wcolH;
            if ((unsigned)hp < 128u && (unsigned)gc < 128u) {
                const float* px = xbase + (size_t)(s * 16 + ic8H * 8) * 16384 + hp * 128 + gc;
                #pragma unroll
                for (int j = 0; j < 8; ++j) pfh[j] = px[(size_t)j * 16384];
            } else {
                #pragma unroll
                for (int j = 0; j < 8; ++j) pfh[j] = 0.f;
            }
        }
    };

    auto WRITE = [&](auto Uc, auto WBc) {
        constexpr int U  = decltype(Uc)::value;
        constexpr int WB = decltype(WBc)::value;
        u32x4 v;
        v[0] = pack2bf(pf[U][0], pf[U][1]);
        v[1] = pack2bf(pf[U][2], pf[U][3]);
        v[2] = pack2bf(pf[U][4], pf[U][5]);
        v[3] = pack2bf(pf[U][6], pf[U][7]);
        *reinterpret_cast<u32x4*>(&lds[WB * LDSBUF + (2 * U + rh) * LDSROW
                                       + (wc + 2) * 48 + ic8 * 16]) = v;
    };

    auto WRITEH = [&](auto WBc) {
        constexpr int WB = decltype(WBc)::value;
        if (tid < 64) {
            u32x4 v;
            v[0] = pack2bf(pfh[0], pfh[1]);
            v[1] = pack2bf(pfh[2], pfh[3]);
            v[2] = pack2bf(pfh[4], pfh[5]);
            v[3] = pack2bf(pfh[6], pfh[7]);
            *reinterpret_cast<u32x4*>(&lds[WB * LDSBUF + rH * LDSROW
                                           + hIdxH * 48 + ic8H * 16]) = v;
        }
    };

    auto COMPUTE = [&](auto Pc, auto KWc, auto RBc) {     // 8 ds_read -> 20 MFMA
        constexpr int P  = decltype(Pc)::value;
        constexpr int KW = decltype(KWc)::value;
        constexpr int RB = decltype(RBc)::value;
        const unsigned char* lbase = &lds[RB * LDSBUF
                                          + (wave_q * 32 + l31 + KW) * 48 + h2 * 16];
        __builtin_amdgcn_s_setprio(1);
        #pragma unroll
        for (int rp = 0; rp < 8; ++rp) {
            const bf16x8 b = *reinterpret_cast<const bf16x8*>(lbase + rp * LDSROW);
            #pragma unroll
            for (int kh = 0; kh < 5; ++kh) {
                const int n = rp - kh;
                if (0 <= n && n < 4)
                    acc[n] = __builtin_amdgcn_mfma_f32_32x32x16_bf16(A[P][kh], b, acc[n], 0, 0, 0);
            }
        }
        __builtin_amdgcn_s_setprio(0);
    };

    // stage-end barrier: order LDS, do NOT drain vmcnt (A-prefetch crosses)
    auto SBAR = [&]() {
        asm volatile("s_waitcnt lgkmcnt(0)" ::: "memory");
        __builtin_amdgcn_s_barrier();
        __builtin_amdgcn_sched_barrier(0);
    };

    // prologue: stage 0 into buf 0; A for (s=0, c0) into parity 0
    ISSUE(IC<0>{}, 0); ISSUE(IC<1>{}, 0); ISSUE(IC<2>{}, 0); ISSUE(IC<3>{}, 0); ISSUEH(0);
    WRITE(IC<0>{}, IC<0>{}); WRITE(IC<1>{}, IC<0>{});
    WRITE(IC<2>{}, IC<0>{}); WRITE(IC<3>{}, IC<0>{}); WRITEH(IC<0>{});
    ALOAD(IC<0>{}, IC<0>{}, 0);
    __syncthreads();

    // stage s: cluster k uses A[(k+s)&1]; reads buf s&1; stages s+1 into buf (s+1)&1
    auto STAGE = [&](auto SPc, int s) {
        constexpr int SP = decltype(SPc)::value;         // = s & 1
        constexpr int RB = SP;                           // read buffer
        constexpr int WB = SP ^ 1;                       // write buffer
        const bool pfon = (s < 7);
        // k=0
        ALOAD(IC<(1 + SP) & 1>{}, IC<1>{}, s);
        if (pfon) ISSUE(IC<0>{}, s + 1);
        COMPUTE(IC<SP>{}, IC<0>{}, IC<RB>{});
        // k=1
        ALOAD(IC<SP>{}, IC<2>{}, s);
        if (pfon) ISSUE(IC<1>{}, s + 1);
        COMPUTE(IC<(1 + SP) & 1>{}, IC<1>{}, IC<RB>{});
        if (pfon) WRITE(IC<0>{}, IC<WB>{});
        // k=2
        ALOAD(IC<(1 + SP) & 1>{}, IC<3>{}, s);
        if (pfon) ISSUE(IC<2>{}, s + 1);
        COMPUTE(IC<SP>{}, IC<2>{}, IC<RB>{});
        if (pfon) WRITE(IC<1>{}, IC<WB>{});
        // k=3
        ALOAD(IC<SP>{}, IC<4>{}, s);
        if (pfon) { ISSUE(IC<3>{}, s + 1); ISSUEH(s + 1); }
        COMPUTE(IC<(1 + SP) & 1>{}, IC<3>{}, IC<RB>{});
        if (pfon) WRITE(IC<2>{}, IC<WB>{});
        // k=4
        if (pfon) ALOAD(IC<(1 + SP) & 1>{}, IC<0>{}, s + 1);   // next stage c0
        COMPUTE(IC<SP>{}, IC<4>{}, IC<RB>{});
        if (pfon) { WRITE(IC<3>{}, IC<WB>{}); WRITEH(IC<WB>{}); }
        SBAR();
    };

    #pragma unroll 1
    for (int sp = 0; sp < 4; ++sp) {
        STAGE(IC<0>{}, 2 * sp);
        STAGE(IC<1>{}, 2 * sp + 1);
    }

    // epilogue: D frag (32x32): col=lane&31 -> w, row=(reg&3)+8*(reg>>2)+4*h2 -> oc
    const int wpix = w0 + wave_q * 32 + l31;
    #pragma unroll
    for (int reg = 0; reg < 16; ++reg) {
        const int oc = ocb + wave_m * 32 + (reg & 3) + ((reg >> 2) << 3) + (h2 << 2);
        float* op = out + ((size_t)(bb * 128 + oc) * 128 + h0) * 128 + wpix;
        #pragma unroll
        for (int n = 0; n < 4; ++n)
            op[n * 128] = acc[n][reg];
    }
}

extern "C" void kernel_launch(void* const* d_in, const int* in_sizes, int n_in,
                              void* d_out, int out_size, void* d_ws, size_t ws_size,
                              hipStream_t stream)
{
    const float* x    = (const float*)d_in[0];
    const float* wxx  = (const float*)d_in[1];
    const float* wi   = (const float*)d_in[2];
    const float* XX   = (const float*)d_in[3];
    const float* iden = (const float*)d_in[4];
    const int*   ixx  = (const int*)d_in[5];
    const int*   iid  = (const int*)d_in[6];

    u16* cbuf = (u16*)d_ws;                              // 819200 B scratch

    build_c<<<1600, 256, 0, stream>>>(wxx, wi, XX, iden, ixx, iid, cbuf);
    conv_mfma<<<2048, 256, 0, stream>>>(x, cbuf, (float*)d_out);
}